// Round 1
// baseline (853.958 us; speedup 1.0000x reference)
//
#include <hip/hip_runtime.h>
#include <stdint.h>
#include <stddef.h>

#define E_ 8
#define B_ 4096
#define DIN 1024
#define DHID 2048
#define DOUT 1024

#define RMAX 9216      // 8192 assignments + worst-case 128-alignment padding
#define NTILES 72      // RMAX / 128

// d_out layout (fp32): combined[4096*1024], aux[1], idx[4096*2], scores[4096*2]
#define OUT_AUX  4194304
#define OUT_IDX  4194305
#define OUT_SC   4202497

using f32x4  = __attribute__((ext_vector_type(4))) float;
using bf16x8 = __attribute__((ext_vector_type(8))) short;

static __device__ __forceinline__ unsigned short f2bf(float f) {
  unsigned int u = __builtin_bit_cast(unsigned int, f);
  u += 0x7FFFu + ((u >> 16) & 1u);   // RNE (no NaNs in this data)
  return (unsigned short)(u >> 16);
}

#define GLOAD_LDS(gp, lp) __builtin_amdgcn_global_load_lds( \
    (const __attribute__((address_space(1))) void*)(gp),    \
    (__attribute__((address_space(3))) void*)(lp), 16, 0, 0)

// ---------------------------------------------------------------- init
__global__ void k_init(int* counts, int* cnt2, float* esum) {
  int t = threadIdx.x;
  if (t < E_) { counts[t] = 0; cnt2[t] = 0; }
  if (t == 0) esum[0] = 0.f;
}

// ------------------------------------------- fp32->bf16 transpose-convert
// W: [E][K][N] row-major  ->  Wt: [E][N][K] row-major (bf16 bits)
__global__ void k_conv(const float* __restrict__ W, unsigned short* __restrict__ Wt,
                       int K, int N) {
  __shared__ float tile[32][33];
  const int e = blockIdx.z;
  const float* We = W + (size_t)e * K * N;
  unsigned short* Wte = Wt + (size_t)e * N * K;
  const int k0 = blockIdx.x * 32, n0 = blockIdx.y * 32;
  const int tx = threadIdx.x, ty = threadIdx.y;   // (32, 8)
  #pragma unroll
  for (int j = 0; j < 32; j += 8)
    tile[ty + j][tx] = We[(size_t)(k0 + ty + j) * N + n0 + tx];
  __syncthreads();
  #pragma unroll
  for (int j = 0; j < 32; j += 8)
    Wte[(size_t)(n0 + ty + j) * K + k0 + tx] = f2bf(tile[tx][ty + j]);
}

// ---------------------------------------------------------------- gate
// 256 threads (4 waves), 16 rows/block. fp64 accumulation, fp32 intermediates.
__global__ __launch_bounds__(256) void k_gate(
    const float* __restrict__ x,
    const float* __restrict__ Wg1, const float* __restrict__ bg1,
    const float* __restrict__ Wg2, const float* __restrict__ bg2,
    const float* __restrict__ Wg3, const float* __restrict__ bg3,
    float* __restrict__ dout, int* __restrict__ counts, float* __restrict__ esum)
{
  __shared__ __align__(16) float xs[16][1024];
  __shared__ __align__(16) float g1s[16][128];
  __shared__ __align__(16) float g2s[16][128];
  __shared__ float ls[16][8];
  const int t = threadIdx.x;
  const int b0 = blockIdx.x * 16;

  { // stage 16 x-rows
    const f32x4* xg = (const f32x4*)(x + (size_t)b0 * DIN);
    f32x4* xl = (f32x4*)&xs[0][0];
    #pragma unroll
    for (int i = 0; i < 16; i++) xl[t + i * 256] = xg[t + i * 256];
  }
  __syncthreads();

  const int w = t >> 6, l = t & 63;
  const int r0 = w * 4;             // wave w owns rows r0..r0+3; lane owns cols l, l+64
  double a0[4], a1[4];

  // ---- layer 1: 1024 -> 128, relu ----
  {
    const double bA = (double)bg1[l], bB = (double)bg1[64 + l];
    #pragma unroll
    for (int r = 0; r < 4; r++) { a0[r] = bA; a1[r] = bB; }
    for (int i = 0; i < 1024; i += 4) {
      f32x4 xv[4];
      #pragma unroll
      for (int r = 0; r < 4; r++) xv[r] = *(const f32x4*)&xs[r0 + r][i];
      #pragma unroll
      for (int q = 0; q < 4; q++) {
        const double w0 = (double)Wg1[(size_t)(i + q) * 128 + l];
        const double w1 = (double)Wg1[(size_t)(i + q) * 128 + 64 + l];
        #pragma unroll
        for (int r = 0; r < 4; r++) {
          a0[r] += (double)xv[r][q] * w0;
          a1[r] += (double)xv[r][q] * w1;
        }
      }
    }
    #pragma unroll
    for (int r = 0; r < 4; r++) {
      g1s[r0 + r][l]      = fmaxf((float)a0[r], 0.f);
      g1s[r0 + r][64 + l] = fmaxf((float)a1[r], 0.f);
    }
  }
  __syncthreads();

  // ---- layer 2: 128 -> 128, relu ----
  {
    const double bA = (double)bg2[l], bB = (double)bg2[64 + l];
    #pragma unroll
    for (int r = 0; r < 4; r++) { a0[r] = bA; a1[r] = bB; }
    for (int j = 0; j < 128; j += 4) {
      f32x4 gv[4];
      #pragma unroll
      for (int r = 0; r < 4; r++) gv[r] = *(const f32x4*)&g1s[r0 + r][j];
      #pragma unroll
      for (int q = 0; q < 4; q++) {
        const double w0 = (double)Wg2[(size_t)(j + q) * 128 + l];
        const double w1 = (double)Wg2[(size_t)(j + q) * 128 + 64 + l];
        #pragma unroll
        for (int r = 0; r < 4; r++) {
          a0[r] += (double)gv[r][q] * w0;
          a1[r] += (double)gv[r][q] * w1;
        }
      }
    }
    #pragma unroll
    for (int r = 0; r < 4; r++) {
      g2s[r0 + r][l]      = fmaxf((float)a0[r], 0.f);
      g2s[r0 + r][64 + l] = fmaxf((float)a1[r], 0.f);
    }
  }
  __syncthreads();

  // ---- logits: 128 -> 8 ----
  if (t < 128) {
    const int r = t >> 3, e = t & 7;
    double a = (double)bg3[e];
    for (int j = 0; j < 128; j++)
      a += (double)g2s[r][j] * (double)Wg3[j * 8 + e];
    ls[r][e] = (float)a;
  }
  __syncthreads();

  // ---- softmax / top-2 / entropy (1 thread per row) ----
  if (t < 16) {
    const int b = b0 + t;
    float lg[8], p[8];
    float m = -3.4e38f;
    #pragma unroll
    for (int e = 0; e < 8; e++) { lg[e] = ls[t][e]; m = fmaxf(m, lg[e]); }
    float s = 0.f;
    #pragma unroll
    for (int e = 0; e < 8; e++) { p[e] = expf(lg[e] - m); s += p[e]; }
    #pragma unroll
    for (int e = 0; e < 8; e++) p[e] = p[e] / s;
    int i0 = 0;
    #pragma unroll
    for (int e = 1; e < 8; e++) if (p[e] > p[i0]) i0 = e;
    int i1 = (i0 == 0) ? 1 : 0;
    #pragma unroll
    for (int e = 0; e < 8; e++) if (e != i0 && p[e] > p[i1]) i1 = e;
    float ent = 0.f;
    #pragma unroll
    for (int e = 0; e < 8; e++) ent -= p[e] * logf(p[e] + 1e-9f);
    dout[OUT_IDX + (size_t)b * 2 + 0] = (float)i0;
    dout[OUT_IDX + (size_t)b * 2 + 1] = (float)i1;
    dout[OUT_SC  + (size_t)b * 2 + 0] = p[i0];
    dout[OUT_SC  + (size_t)b * 2 + 1] = p[i1];
    atomicAdd(&counts[i0], 1);
    atomicAdd(&counts[i1], 1);
    atomicAdd(esum, ent);
  }
}

// -------------------------------------------- offsets + tile table + aux
__global__ void k_offsets(const int* __restrict__ counts, int* __restrict__ seg,
                          int* __restrict__ tilee, const float* __restrict__ esum,
                          float* __restrict__ dout) {
  if (threadIdx.x != 0 || blockIdx.x != 0) return;
  for (int t = 0; t < NTILES; t++) tilee[t] = -1;
  int s = 0;
  float loads[E_];
  float mean = 0.f;
  for (int e = 0; e < E_; e++) {
    const int c = counts[e];
    seg[e] = s;
    const int tiles = (c + 127) >> 7;
    for (int lt = 0; lt < tiles; lt++) tilee[(s >> 7) + lt] = e;
    s += tiles << 7;
    loads[e] = (float)c / 4096.0f;
    mean += loads[e];
  }
  seg[E_] = s;
  mean *= 0.125f;
  float var = 0.f;
  for (int e = 0; e < E_; e++) { const float d = loads[e] - mean; var += d * d; }
  var /= 7.0f;
  dout[OUT_AUX] = 5.0f * var + 0.1f * (esum[0] / 4096.0f);
}

// ---------------------------------------------------------------- scatter
__global__ void k_scatter(const float* __restrict__ dout, int* __restrict__ posmap,
                          float* __restrict__ wgt, int* __restrict__ cnt2,
                          const int* __restrict__ seg) {
  const int a = blockIdx.x * 256 + threadIdx.x;
  if (a >= B_ * 2) return;
  const int b = a >> 1;
  const int e = (int)dout[OUT_IDX + a];
  const float sc = dout[OUT_SC + a];
  const float denom = dout[OUT_SC + b * 2] + dout[OUT_SC + b * 2 + 1] + 1e-9f;
  const int p = seg[e] + atomicAdd(&cnt2[e], 1);
  posmap[a] = p;
  wgt[p] = sc / denom;
}

// ---------------------------------------------------------------- gather
__global__ void k_gather(const float* __restrict__ x, const int* __restrict__ posmap,
                         unsigned short* __restrict__ Xg) {
  const int a = blockIdx.x, t = threadIdx.x;   // 128 threads
  const int b = a >> 1;
  const int p = posmap[a];
  const f32x4* xr = (const f32x4*)(x + (size_t)b * DIN);
  const f32x4 v0 = xr[t * 2], v1 = xr[t * 2 + 1];
  bf16x8 s;
  s[0] = (short)f2bf(v0[0]); s[1] = (short)f2bf(v0[1]);
  s[2] = (short)f2bf(v0[2]); s[3] = (short)f2bf(v0[3]);
  s[4] = (short)f2bf(v1[0]); s[5] = (short)f2bf(v1[1]);
  s[6] = (short)f2bf(v1[2]); s[7] = (short)f2bf(v1[3]);
  ((bf16x8*)(Xg + (size_t)p * DIN))[t] = s;
}

// ------------------------------------------------------------- grouped GEMM
// C[m][n] = relu?(A[m][:] * Wt_e[n][:] + bias_e[n]) ; 128x128 tile, BK=32,
// 4 waves of 4x4 16x16x32 MFMA fragments, global_load_lds width 16.
template<bool RELU, bool OUTF32>
__global__ __launch_bounds__(256) void k_gemm(
    const unsigned short* __restrict__ A, int lda,
    const unsigned short* __restrict__ Wt,
    const float* __restrict__ bias,
    void* __restrict__ Cv, int N, int K,
    const int* __restrict__ tilee)
{
  const int e = tilee[blockIdx.x];
  if (e < 0) return;
  __shared__ __align__(16) unsigned short As[128 * 32];
  __shared__ __align__(16) unsigned short Bs[128 * 32];
  const int tid = threadIdx.x;
  const int m0 = blockIdx.x * 128;
  const int n0 = blockIdx.y * 128;
  const unsigned short* __restrict__ Ab = A + (size_t)m0 * lda;
  const unsigned short* __restrict__ Bb = Wt + (size_t)e * N * K + (size_t)n0 * K;

  const int c0 = tid, c1 = tid + 256;
  const int ar0 = c0 >> 2, ak0 = (c0 & 3) * 8;
  const int ar1 = c1 >> 2, ak1 = (c1 & 3) * 8;

  const int lane = tid & 63;
  const int wid  = tid >> 6;
  const int wm = wid >> 1, wn = wid & 1;
  const int fr = lane & 15, g = lane >> 4;

  const f32x4 zero = {0.f, 0.f, 0.f, 0.f};
  f32x4 acc[4][4];
  #pragma unroll
  for (int m = 0; m < 4; m++)
    #pragma unroll
    for (int n = 0; n < 4; n++) acc[m][n] = zero;

  const bf16x8* As8 = (const bf16x8*)As;
  const bf16x8* Bs8 = (const bf16x8*)Bs;

  for (int k0 = 0; k0 < K; k0 += 32) {
    GLOAD_LDS(Ab + (size_t)ar0 * lda + k0 + ak0, &As[c0 * 8]);
    GLOAD_LDS(Ab + (size_t)ar1 * lda + k0 + ak1, &As[c1 * 8]);
    GLOAD_LDS(Bb + (size_t)ar0 * K   + k0 + ak0, &Bs[c0 * 8]);
    GLOAD_LDS(Bb + (size_t)ar1 * K   + k0 + ak1, &Bs[c1 * 8]);
    __syncthreads();                       // drains vmcnt; LDS tiles ready
    bf16x8 av[4], bv[4];
    #pragma unroll
    for (int m = 0; m < 4; m++) av[m] = As8[(wm * 64 + m * 16 + fr) * 4 + g];
    #pragma unroll
    for (int n = 0; n < 4; n++) bv[n] = Bs8[(wn * 64 + n * 16 + fr) * 4 + g];
    __syncthreads();                       // all frags read -> next stage may overwrite
    #pragma unroll
    for (int m = 0; m < 4; m++)
      #pragma unroll
      for (int n = 0; n < 4; n++)
        acc[m][n] = __builtin_amdgcn_mfma_f32_16x16x32_bf16(av[m], bv[n], acc[m][n], 0, 0, 0);
  }

  float* Cf = (float*)Cv;
  unsigned short* Ch = (unsigned short*)Cv;
  #pragma unroll
  for (int n = 0; n < 4; n++) {
    const int col = n0 + wn * 64 + n * 16 + fr;
    const float bvv = bias[(size_t)e * N + col];
    #pragma unroll
    for (int m = 0; m < 4; m++) {
      const int row = m0 + wm * 64 + m * 16 + g * 4;
      #pragma unroll
      for (int r = 0; r < 4; r++) {
        float v = acc[m][n][r] + bvv;
        if (RELU) v = fmaxf(v, 0.f);
        if (OUTF32) Cf[(size_t)(row + r) * N + col] = v;
        else        Ch[(size_t)(row + r) * N + col] = f2bf(v);
      }
    }
  }
}

// ---------------------------------------------------------------- combine
__global__ void k_combine(const float* __restrict__ Yg, const int* __restrict__ posmap,
                          const float* __restrict__ wgt, float* __restrict__ out) {
  const int b = blockIdx.x, t = threadIdx.x;   // 256 threads x float4 = 1024
  const int p0 = posmap[b * 2], p1 = posmap[b * 2 + 1];
  const float w0 = wgt[p0], w1 = wgt[p1];
  const f32x4 y0 = ((const f32x4*)(Yg + (size_t)p0 * DOUT))[t];
  const f32x4 y1 = ((const f32x4*)(Yg + (size_t)p1 * DOUT))[t];
  f32x4 o = y0 * w0 + y1 * w1;
  ((f32x4*)(out + (size_t)b * DOUT))[t] = o;
}

// ---------------------------------------------------------------- launch
extern "C" void kernel_launch(void* const* d_in, const int* in_sizes, int n_in,
                              void* d_out, int out_size, void* d_ws, size_t ws_size,
                              hipStream_t stream) {
  (void)in_sizes; (void)n_in; (void)out_size; (void)ws_size;
  const float* x   = (const float*)d_in[0];
  const float* We1 = (const float*)d_in[1];
  const float* be1 = (const float*)d_in[2];
  const float* We2 = (const float*)d_in[3];
  const float* be2 = (const float*)d_in[4];
  const float* We3 = (const float*)d_in[5];
  const float* be3 = (const float*)d_in[6];
  const float* Wg1 = (const float*)d_in[7];
  const float* bg1 = (const float*)d_in[8];
  const float* Wg2 = (const float*)d_in[9];
  const float* bg2 = (const float*)d_in[10];
  const float* Wg3 = (const float*)d_in[11];
  const float* bg3 = (const float*)d_in[12];
  float* out = (float*)d_out;

  char* ws = (char*)d_ws;
  size_t off = 0;
  auto alloc = [&](size_t bytes) {
    char* p = ws + off;
    off += (bytes + 255) & ~(size_t)255;
    return p;
  };
  unsigned short* WT1 = (unsigned short*)alloc((size_t)E_ * DHID * DIN * 2);
  unsigned short* WT2 = (unsigned short*)alloc((size_t)E_ * DHID * DHID * 2);
  unsigned short* WT3 = (unsigned short*)alloc((size_t)E_ * DOUT * DHID * 2);
  unsigned short* XG  = (unsigned short*)alloc((size_t)RMAX * DIN * 2);
  unsigned short* H1  = (unsigned short*)alloc((size_t)RMAX * DHID * 2);
  unsigned short* H2  = (unsigned short*)alloc((size_t)RMAX * DHID * 2);
  int*   posmap = (int*)alloc((size_t)B_ * 2 * 4);
  float* wgt    = (float*)alloc((size_t)RMAX * 4);
  int*   counts = (int*)alloc(256);
  int*   cnt2   = (int*)alloc(256);
  int*   seg    = (int*)alloc(256);
  int*   tilee  = (int*)alloc(512);
  float* esum   = (float*)alloc(256);
  float* Yg = (float*)H1;   // L3 output reuses H1's space (H1 dead by then)

  k_init<<<1, 64, 0, stream>>>(counts, cnt2, esum);
  k_conv<<<dim3(DIN / 32, DHID / 32, E_), dim3(32, 8), 0, stream>>>(We1, WT1, DIN, DHID);
  k_conv<<<dim3(DHID / 32, DHID / 32, E_), dim3(32, 8), 0, stream>>>(We2, WT2, DHID, DHID);
  k_conv<<<dim3(DHID / 32, DOUT / 32, E_), dim3(32, 8), 0, stream>>>(We3, WT3, DHID, DOUT);
  k_gate<<<B_ / 16, 256, 0, stream>>>(x, Wg1, bg1, Wg2, bg2, Wg3, bg3, out, counts, esum);
  k_offsets<<<1, 1, 0, stream>>>(counts, seg, tilee, esum, out);
  k_scatter<<<(B_ * 2) / 256, 256, 0, stream>>>(out, posmap, wgt, cnt2, seg);
  k_gather<<<B_ * 2, 128, 0, stream>>>(x, posmap, XG);
  k_gemm<true,  false><<<dim3(NTILES, DHID / 128), 256, 0, stream>>>(XG, DIN,  WT1, be1, (void*)H1, DHID, DIN,  tilee);
  k_gemm<true,  false><<<dim3(NTILES, DHID / 128), 256, 0, stream>>>(H1, DHID, WT2, be2, (void*)H2, DHID, DHID, tilee);
  k_gemm<false, true ><<<dim3(NTILES, DOUT / 128), 256, 0, stream>>>(H2, DHID, WT3, be3, (void*)Yg, DOUT, DHID, tilee);
  k_combine<<<B_, 256, 0, stream>>>(Yg, posmap, wgt, out);
}

// Round 2
// 754.956 us; speedup vs baseline: 1.1311x; 1.1311x over previous
//
#include <hip/hip_runtime.h>
#include <stdint.h>
#include <stddef.h>

#define E_ 8
#define B_ 4096
#define DIN 1024
#define DHID 2048
#define DOUT 1024

#define RMAX 9216      // 8192 assignments + worst-case 128-alignment padding
#define NTILES 72      // RMAX / 128

// d_out layout (fp32): combined[4096*1024], aux[1], idx[4096*2], scores[4096*2]
#define OUT_AUX  4194304
#define OUT_IDX  4194305
#define OUT_SC   4202497

using f32x4  = __attribute__((ext_vector_type(4))) float;
using bf16x8 = __attribute__((ext_vector_type(8))) short;

static __device__ __forceinline__ unsigned short f2bf(float f) {
  unsigned int u = __builtin_bit_cast(unsigned int, f);
  u += 0x7FFFu + ((u >> 16) & 1u);   // RNE (no NaNs in this data)
  return (unsigned short)(u >> 16);
}

#define GLOAD_LDS(gp, lp) __builtin_amdgcn_global_load_lds( \
    (const __attribute__((address_space(1))) void*)(gp),    \
    (__attribute__((address_space(3))) void*)(lp), 16, 0, 0)

// ---------------------------------------------------------------- init
__global__ void k_init(int* counts, int* cnt2, float* esum) {
  int t = threadIdx.x;
  if (t < E_) { counts[t] = 0; cnt2[t] = 0; }
  if (t == 0) esum[0] = 0.f;
}

// ------------------------------------------- fp32->bf16 transpose-convert
// W: [E][K][N] row-major  ->  Wt: [E][N][K] row-major (bf16 bits)
// 64(k) x 32(n) tile; ushort2 writes -> fully coalesced 128B/wave stores.
__global__ void k_conv(const float* __restrict__ W, unsigned short* __restrict__ Wt,
                       int K, int N) {
  __shared__ float tile[64][33];
  const int e = blockIdx.z;
  const float* We = W + (size_t)e * K * N;
  unsigned short* Wte = Wt + (size_t)e * N * K;
  const int k0 = blockIdx.x * 64, n0 = blockIdx.y * 32;
  const int tx = threadIdx.x, ty = threadIdx.y;   // (32, 8)
  #pragma unroll
  for (int j = 0; j < 64; j += 8)
    tile[ty + j][tx] = We[(size_t)(k0 + ty + j) * N + n0 + tx];
  __syncthreads();
  #pragma unroll
  for (int j = 0; j < 32; j += 8) {
    const int n = ty + j;
    const unsigned int lo = f2bf(tile[2 * tx][n]);
    const unsigned int hi = f2bf(tile[2 * tx + 1][n]);
    *(unsigned int*)&Wte[(size_t)(n0 + n) * K + k0 + 2 * tx] = lo | (hi << 16);
  }
}

// ---------------------------------------------------------------- gate
// 4 rows/block x 1024 blocks, 256 threads. fp64 accumulation, fp32 rounding
// at exactly the reference's rounding points (relu outputs, logits).
// x staged as double in LDS (one cvt per element, not per use).
// Thread t owns column c = t&127 for rows {rr, rr+2}, rr = t>>7.
__global__ __launch_bounds__(256) void k_gate(
    const float* __restrict__ x,
    const float* __restrict__ Wg1, const float* __restrict__ bg1,
    const float* __restrict__ Wg2, const float* __restrict__ bg2,
    const float* __restrict__ Wg3, const float* __restrict__ bg3,
    float* __restrict__ dout, int* __restrict__ counts, float* __restrict__ esum)
{
  __shared__ __align__(16) double xs[4][1024];
  __shared__ __align__(16) float g1s[4][128];
  __shared__ __align__(16) float g2s[4][128];
  __shared__ float ls[4][8];
  const int t = threadIdx.x;
  const int b0 = blockIdx.x * 4;

  { // stage 4 x-rows as double
    const float2* xg = (const float2*)(x + (size_t)b0 * DIN);
    double2* xl = (double2*)&xs[0][0];
    #pragma unroll
    for (int i = 0; i < 8; i++) {
      const float2 v = xg[t + i * 256];
      double2 d; d.x = (double)v.x; d.y = (double)v.y;
      xl[t + i * 256] = d;
    }
  }
  __syncthreads();

  const int c = t & 127, rr = t >> 7;

  // ---- layer 1: 1024 -> 128, relu ----
  {
    double a0 = (double)bg1[c], a1 = a0;
    const float* wp = Wg1 + c;
    for (int i = 0; i < 1024; i += 4) {
      const float w0 = wp[(size_t)(i + 0) * 128];
      const float w1 = wp[(size_t)(i + 1) * 128];
      const float w2 = wp[(size_t)(i + 2) * 128];
      const float w3 = wp[(size_t)(i + 3) * 128];
      const double2* xr0 = (const double2*)&xs[rr][i];
      const double2* xr2 = (const double2*)&xs[rr + 2][i];
      const double2 xa = xr0[0], xb = xr0[1];
      const double2 xc = xr2[0], xd = xr2[1];
      a0 += (double)w0 * xa.x; a1 += (double)w0 * xc.x;
      a0 += (double)w1 * xa.y; a1 += (double)w1 * xc.y;
      a0 += (double)w2 * xb.x; a1 += (double)w2 * xd.x;
      a0 += (double)w3 * xb.y; a1 += (double)w3 * xd.y;
    }
    g1s[rr][c]     = fmaxf((float)a0, 0.f);
    g1s[rr + 2][c] = fmaxf((float)a1, 0.f);
  }
  __syncthreads();

  // ---- layer 2: 128 -> 128, relu ----
  {
    double a0 = (double)bg2[c], a1 = a0;
    const float* wp = Wg2 + c;
    for (int j = 0; j < 128; j += 4) {
      const float w0 = wp[(size_t)(j + 0) * 128];
      const float w1 = wp[(size_t)(j + 1) * 128];
      const float w2 = wp[(size_t)(j + 2) * 128];
      const float w3 = wp[(size_t)(j + 3) * 128];
      const f32x4 ga = *(const f32x4*)&g1s[rr][j];
      const f32x4 gb = *(const f32x4*)&g1s[rr + 2][j];
      a0 += (double)w0 * (double)ga[0]; a1 += (double)w0 * (double)gb[0];
      a0 += (double)w1 * (double)ga[1]; a1 += (double)w1 * (double)gb[1];
      a0 += (double)w2 * (double)ga[2]; a1 += (double)w2 * (double)gb[2];
      a0 += (double)w3 * (double)ga[3]; a1 += (double)w3 * (double)gb[3];
    }
    g2s[rr][c]     = fmaxf((float)a0, 0.f);
    g2s[rr + 2][c] = fmaxf((float)a1, 0.f);
  }
  __syncthreads();

  // ---- logits: 128 -> 8 ----
  if (t < 32) {
    const int r = t >> 3, e = t & 7;
    double a = (double)bg3[e];
    for (int j = 0; j < 128; j++)
      a += (double)g2s[r][j] * (double)Wg3[j * 8 + e];
    ls[r][e] = (float)a;
  }
  __syncthreads();

  // ---- softmax / top-2 / entropy (1 thread per row) ----
  if (t < 4) {
    const int b = b0 + t;
    float lg[8], p[8];
    float m = -3.4e38f;
    #pragma unroll
    for (int e = 0; e < 8; e++) { lg[e] = ls[t][e]; m = fmaxf(m, lg[e]); }
    float s = 0.f;
    #pragma unroll
    for (int e = 0; e < 8; e++) { p[e] = expf(lg[e] - m); s += p[e]; }
    #pragma unroll
    for (int e = 0; e < 8; e++) p[e] = p[e] / s;
    int i0 = 0;
    #pragma unroll
    for (int e = 1; e < 8; e++) if (p[e] > p[i0]) i0 = e;
    int i1 = (i0 == 0) ? 1 : 0;
    #pragma unroll
    for (int e = 0; e < 8; e++) if (e != i0 && p[e] > p[i1]) i1 = e;
    float ent = 0.f;
    #pragma unroll
    for (int e = 0; e < 8; e++) ent -= p[e] * logf(p[e] + 1e-9f);
    dout[OUT_IDX + (size_t)b * 2 + 0] = (float)i0;
    dout[OUT_IDX + (size_t)b * 2 + 1] = (float)i1;
    dout[OUT_SC  + (size_t)b * 2 + 0] = p[i0];
    dout[OUT_SC  + (size_t)b * 2 + 1] = p[i1];
    atomicAdd(&counts[i0], 1);
    atomicAdd(&counts[i1], 1);
    atomicAdd(esum, ent);
  }
}

// -------------------------------------------- offsets + tile table + aux
__global__ void k_offsets(const int* __restrict__ counts, int* __restrict__ seg,
                          int* __restrict__ tilee, const float* __restrict__ esum,
                          float* __restrict__ dout) {
  if (threadIdx.x != 0 || blockIdx.x != 0) return;
  for (int t = 0; t < NTILES; t++) tilee[t] = -1;
  int s = 0;
  float loads[E_];
  float mean = 0.f;
  for (int e = 0; e < E_; e++) {
    const int c = counts[e];
    seg[e] = s;
    const int tiles = (c + 127) >> 7;
    for (int lt = 0; lt < tiles; lt++) tilee[(s >> 7) + lt] = e;
    s += tiles << 7;
    loads[e] = (float)c / 4096.0f;
    mean += loads[e];
  }
  seg[E_] = s;
  mean *= 0.125f;
  float var = 0.f;
  for (int e = 0; e < E_; e++) { const float d = loads[e] - mean; var += d * d; }
  var /= 7.0f;
  dout[OUT_AUX] = 5.0f * var + 0.1f * (esum[0] / 4096.0f);
}

// ---------------------------------------------------------------- scatter
__global__ void k_scatter(const float* __restrict__ dout, int* __restrict__ posmap,
                          float* __restrict__ wgt, int* __restrict__ cnt2,
                          const int* __restrict__ seg) {
  const int a = blockIdx.x * 256 + threadIdx.x;
  if (a >= B_ * 2) return;
  const int b = a >> 1;
  const int e = (int)dout[OUT_IDX + a];
  const float sc = dout[OUT_SC + a];
  const float denom = dout[OUT_SC + b * 2] + dout[OUT_SC + b * 2 + 1] + 1e-9f;
  const int p = seg[e] + atomicAdd(&cnt2[e], 1);
  posmap[a] = p;
  wgt[p] = sc / denom;
}

// ---------------------------------------------------------------- gather
__global__ void k_gather(const float* __restrict__ x, const int* __restrict__ posmap,
                         unsigned short* __restrict__ Xg) {
  const int a = blockIdx.x, t = threadIdx.x;   // 128 threads
  const int b = a >> 1;
  const int p = posmap[a];
  const f32x4* xr = (const f32x4*)(x + (size_t)b * DIN);
  const f32x4 v0 = xr[t * 2], v1 = xr[t * 2 + 1];
  bf16x8 s;
  s[0] = (short)f2bf(v0[0]); s[1] = (short)f2bf(v0[1]);
  s[2] = (short)f2bf(v0[2]); s[3] = (short)f2bf(v0[3]);
  s[4] = (short)f2bf(v1[0]); s[5] = (short)f2bf(v1[1]);
  s[6] = (short)f2bf(v1[2]); s[7] = (short)f2bf(v1[3]);
  ((bf16x8*)(Xg + (size_t)p * DIN))[t] = s;
}

// ------------------------------------------------------------- grouped GEMM
// C[m][n] = relu?(A[m][:] * Wt_e[n][:] + bias_e[n]) ; 128x128 tile, BK=32,
// 4 waves of 4x4 16x16x32 MFMA fragments, global_load_lds width 16.
template<bool RELU, bool OUTF32>
__global__ __launch_bounds__(256) void k_gemm(
    const unsigned short* __restrict__ A, int lda,
    const unsigned short* __restrict__ Wt,
    const float* __restrict__ bias,
    void* __restrict__ Cv, int N, int K,
    const int* __restrict__ tilee)
{
  const int e = tilee[blockIdx.x];
  if (e < 0) return;
  __shared__ __align__(16) unsigned short As[128 * 32];
  __shared__ __align__(16) unsigned short Bs[128 * 32];
  const int tid = threadIdx.x;
  const int m0 = blockIdx.x * 128;
  const int n0 = blockIdx.y * 128;
  const unsigned short* __restrict__ Ab = A + (size_t)m0 * lda;
  const unsigned short* __restrict__ Bb = Wt + (size_t)e * N * K + (size_t)n0 * K;

  const int c0 = tid, c1 = tid + 256;
  const int ar0 = c0 >> 2, ak0 = (c0 & 3) * 8;
  const int ar1 = c1 >> 2, ak1 = (c1 & 3) * 8;

  const int lane = tid & 63;
  const int wid  = tid >> 6;
  const int wm = wid >> 1, wn = wid & 1;
  const int fr = lane & 15, g = lane >> 4;

  const f32x4 zero = {0.f, 0.f, 0.f, 0.f};
  f32x4 acc[4][4];
  #pragma unroll
  for (int m = 0; m < 4; m++)
    #pragma unroll
    for (int n = 0; n < 4; n++) acc[m][n] = zero;

  const bf16x8* As8 = (const bf16x8*)As;
  const bf16x8* Bs8 = (const bf16x8*)Bs;

  for (int k0 = 0; k0 < K; k0 += 32) {
    GLOAD_LDS(Ab + (size_t)ar0 * lda + k0 + ak0, &As[c0 * 8]);
    GLOAD_LDS(Ab + (size_t)ar1 * lda + k0 + ak1, &As[c1 * 8]);
    GLOAD_LDS(Bb + (size_t)ar0 * K   + k0 + ak0, &Bs[c0 * 8]);
    GLOAD_LDS(Bb + (size_t)ar1 * K   + k0 + ak1, &Bs[c1 * 8]);
    __syncthreads();                       // drains vmcnt; LDS tiles ready
    bf16x8 av[4], bv[4];
    #pragma unroll
    for (int m = 0; m < 4; m++) av[m] = As8[(wm * 64 + m * 16 + fr) * 4 + g];
    #pragma unroll
    for (int n = 0; n < 4; n++) bv[n] = Bs8[(wn * 64 + n * 16 + fr) * 4 + g];
    __syncthreads();                       // all frags read -> next stage may overwrite
    #pragma unroll
    for (int m = 0; m < 4; m++)
      #pragma unroll
      for (int n = 0; n < 4; n++)
        acc[m][n] = __builtin_amdgcn_mfma_f32_16x16x32_bf16(av[m], bv[n], acc[m][n], 0, 0, 0);
  }

  float* Cf = (float*)Cv;
  unsigned short* Ch = (unsigned short*)Cv;
  #pragma unroll
  for (int n = 0; n < 4; n++) {
    const int col = n0 + wn * 64 + n * 16 + fr;
    const float bvv = bias[(size_t)e * N + col];
    #pragma unroll
    for (int m = 0; m < 4; m++) {
      const int row = m0 + wm * 64 + m * 16 + g * 4;
      #pragma unroll
      for (int r = 0; r < 4; r++) {
        float v = acc[m][n][r] + bvv;
        if (RELU) v = fmaxf(v, 0.f);
        if (OUTF32) Cf[(size_t)(row + r) * N + col] = v;
        else        Ch[(size_t)(row + r) * N + col] = f2bf(v);
      }
    }
  }
}

// ---------------------------------------------------------------- combine
__global__ void k_combine(const float* __restrict__ Yg, const int* __restrict__ posmap,
                          const float* __restrict__ wgt, float* __restrict__ out) {
  const int b = blockIdx.x, t = threadIdx.x;   // 256 threads x float4 = 1024
  const int p0 = posmap[b * 2], p1 = posmap[b * 2 + 1];
  const float w0 = wgt[p0], w1 = wgt[p1];
  const f32x4 y0 = ((const f32x4*)(Yg + (size_t)p0 * DOUT))[t];
  const f32x4 y1 = ((const f32x4*)(Yg + (size_t)p1 * DOUT))[t];
  f32x4 o = y0 * w0 + y1 * w1;
  ((f32x4*)(out + (size_t)b * DOUT))[t] = o;
}

// ---------------------------------------------------------------- launch
extern "C" void kernel_launch(void* const* d_in, const int* in_sizes, int n_in,
                              void* d_out, int out_size, void* d_ws, size_t ws_size,
                              hipStream_t stream) {
  (void)in_sizes; (void)n_in; (void)out_size; (void)ws_size;
  const float* x   = (const float*)d_in[0];
  const float* We1 = (const float*)d_in[1];
  const float* be1 = (const float*)d_in[2];
  const float* We2 = (const float*)d_in[3];
  const float* be2 = (const float*)d_in[4];
  const float* We3 = (const float*)d_in[5];
  const float* be3 = (const float*)d_in[6];
  const float* Wg1 = (const float*)d_in[7];
  const float* bg1 = (const float*)d_in[8];
  const float* Wg2 = (const float*)d_in[9];
  const float* bg2 = (const float*)d_in[10];
  const float* Wg3 = (const float*)d_in[11];
  const float* bg3 = (const float*)d_in[12];
  float* out = (float*)d_out;

  char* ws = (char*)d_ws;
  size_t off = 0;
  auto alloc = [&](size_t bytes) {
    char* p = ws + off;
    off += (bytes + 255) & ~(size_t)255;
    return p;
  };
  unsigned short* WT1 = (unsigned short*)alloc((size_t)E_ * DHID * DIN * 2);
  unsigned short* WT2 = (unsigned short*)alloc((size_t)E_ * DHID * DHID * 2);
  unsigned short* WT3 = (unsigned short*)alloc((size_t)E_ * DOUT * DHID * 2);
  unsigned short* XG  = (unsigned short*)alloc((size_t)RMAX * DIN * 2);
  unsigned short* H1  = (unsigned short*)alloc((size_t)RMAX * DHID * 2);
  unsigned short* H2  = (unsigned short*)alloc((size_t)RMAX * DHID * 2);
  int*   posmap = (int*)alloc((size_t)B_ * 2 * 4);
  float* wgt    = (float*)alloc((size_t)RMAX * 4);
  int*   counts = (int*)alloc(256);
  int*   cnt2   = (int*)alloc(256);
  int*   seg    = (int*)alloc(256);
  int*   tilee  = (int*)alloc(512);
  float* esum   = (float*)alloc(256);
  float* Yg = (float*)H1;   // L3 output reuses H1's space (H1 dead by then)

  k_init<<<1, 64, 0, stream>>>(counts, cnt2, esum);
  k_conv<<<dim3(DIN / 64, DHID / 32, E_), dim3(32, 8), 0, stream>>>(We1, WT1, DIN, DHID);
  k_conv<<<dim3(DHID / 64, DHID / 32, E_), dim3(32, 8), 0, stream>>>(We2, WT2, DHID, DHID);
  k_conv<<<dim3(DHID / 64, DOUT / 32, E_), dim3(32, 8), 0, stream>>>(We3, WT3, DHID, DOUT);
  k_gate<<<B_ / 4, 256, 0, stream>>>(x, Wg1, bg1, Wg2, bg2, Wg3, bg3, out, counts, esum);
  k_offsets<<<1, 1, 0, stream>>>(counts, seg, tilee, esum, out);
  k_scatter<<<(B_ * 2) / 256, 256, 0, stream>>>(out, posmap, wgt, cnt2, seg);
  k_gather<<<B_ * 2, 128, 0, stream>>>(x, posmap, XG);
  k_gemm<true,  false><<<dim3(NTILES, DHID / 128), 256, 0, stream>>>(XG, DIN,  WT1, be1, (void*)H1, DHID, DIN,  tilee);
  k_gemm<true,  false><<<dim3(NTILES, DHID / 128), 256, 0, stream>>>(H1, DHID, WT2, be2, (void*)H2, DHID, DHID, tilee);
  k_gemm<false, true ><<<dim3(NTILES, DOUT / 128), 256, 0, stream>>>(H2, DHID, WT3, be3, (void*)Yg, DOUT, DHID, tilee);
  k_combine<<<B_, 256, 0, stream>>>(Yg, posmap, wgt, out);
}